// Round 2
// baseline (1655.840 us; speedup 1.0000x reference)
//
#include <hip/hip_runtime.h>

#define D 128
#define NPB 64   // nodes per MLP block
#define LDZ 132  // padded LDS row stride (floats)

// ---------------------------------------------------------------------------
// FALLBACK path (workspace too small): legacy atomic scatter.
// ---------------------------------------------------------------------------
__global__ __launch_bounds__(256) void gine_edge_atomic_kernel(
    const float* __restrict__ x, const int* __restrict__ ei,
    const float* __restrict__ ea, float* aggr, int E) {
  long long idx = (long long)blockIdx.x * 256 + threadIdx.x;
  long long total = (long long)E * 32;
  if (idx >= total) return;
  int e = (int)(idx >> 5);
  int c = ((int)idx & 31) << 2;
  int src = ei[e];
  int dst = ei[E + e];
  const float4 xv = *reinterpret_cast<const float4*>(x + (size_t)src * D + c);
  const float4 av = *reinterpret_cast<const float4*>(ea + (size_t)e * D + c);
  float4 m;
  m.x = fmaxf(xv.x + av.x, 0.0f);
  m.y = fmaxf(xv.y + av.y, 0.0f);
  m.z = fmaxf(xv.z + av.z, 0.0f);
  m.w = fmaxf(xv.w + av.w, 0.0f);
  float* base = aggr + (size_t)dst * D + c;
  atomicAdd(base + 0, m.x);
  atomicAdd(base + 1, m.y);
  atomicAdd(base + 2, m.z);
  atomicAdd(base + 3, m.w);
}

// ---------------------------------------------------------------------------
// CSR build step 1: histogram of dst degrees (1.6M int atomics on 400 KB).
// ---------------------------------------------------------------------------
__global__ __launch_bounds__(256) void gine_hist_kernel(
    const int* __restrict__ ei, int* __restrict__ cnt, int E) {
  int e = blockIdx.x * 256 + threadIdx.x;
  if (e >= E) return;
  atomicAdd(&cnt[ei[E + e]], 1);
}

// ---------------------------------------------------------------------------
// CSR build step 2: single-block exclusive scan over N counts.
// 1024 threads, each owns a serial chunk; Hillis-Steele across partials.
// Writes off[0..N] and resets cnt[] to the exclusive prefix (fill cursor).
// ---------------------------------------------------------------------------
__global__ __launch_bounds__(1024) void gine_scan_kernel(
    int* __restrict__ cnt, int* __restrict__ off, int N, int E) {
  __shared__ int part[1024];
  const int t = threadIdx.x;
  const int chunk = (N + 1023) / 1024;
  const int lo = t * chunk;
  const int hi = min(lo + chunk, N);
  int sum = 0;
  for (int i = lo; i < hi; ++i) sum += cnt[i];
  part[t] = sum;
  __syncthreads();
  for (int ofs = 1; ofs < 1024; ofs <<= 1) {
    int v = (t >= ofs) ? part[t - ofs] : 0;
    __syncthreads();
    part[t] += v;
    __syncthreads();
  }
  int p = (t == 0) ? 0 : part[t - 1];  // exclusive prefix for this chunk
  for (int i = lo; i < hi; ++i) {
    int c = cnt[i];
    off[i] = p;
    cnt[i] = p;  // cursor copy for the fill kernel
    p += c;
  }
  if (t == 0) off[N] = E;
}

// ---------------------------------------------------------------------------
// CSR build step 3: scatter edge ids (and pre-resolved src ids) into
// dst-bucketed lists. slist may be null (small-workspace tier).
// ---------------------------------------------------------------------------
__global__ __launch_bounds__(256) void gine_fill_kernel(
    const int* __restrict__ ei, int* __restrict__ cursor,
    int* __restrict__ elist, int* __restrict__ slist, int E) {
  int e = blockIdx.x * 256 + threadIdx.x;
  if (e >= E) return;
  int src = ei[e];
  int dst = ei[E + e];
  int pos = atomicAdd(&cursor[dst], 1);
  elist[pos] = e;
  if (slist) slist[pos] = src;
}

// ---------------------------------------------------------------------------
// Gather-aggregate: one wave per node, lane owns 2 feature columns.
// aggr[i] = sum_{e in CSR[i]} relu(x[src[e]] + ea[e]).  Zero fp32 atomics.
// Each edge row read = 64 lanes x 8 B = 512 B coalesced.
// slist (if present) removes one level of dependent pointer-chase.
// ---------------------------------------------------------------------------
__global__ __launch_bounds__(256) void gine_aggr_kernel(
    const float* __restrict__ x, const float* __restrict__ ea,
    const int* __restrict__ ei, const int* __restrict__ off,
    const int* __restrict__ elist, const int* __restrict__ slist,
    float* __restrict__ aggr, int N) {
  const int node = blockIdx.x * 4 + (threadIdx.x >> 6);
  if (node >= N) return;
  const int lane = threadIdx.x & 63;
  const int c = lane * 2;
  const bool have_s = (slist != nullptr);
  float2 acc = make_float2(0.f, 0.f);
  int j = off[node];
  const int jend = off[node + 1];
  for (; j + 1 < jend; j += 2) {
    int e0 = elist[j];
    int e1 = elist[j + 1];
    int s0 = have_s ? slist[j] : ei[e0];
    int s1 = have_s ? slist[j + 1] : ei[e1];
    const float2 a0 = *reinterpret_cast<const float2*>(ea + (size_t)e0 * D + c);
    const float2 x0 = *reinterpret_cast<const float2*>(x + (size_t)s0 * D + c);
    const float2 a1 = *reinterpret_cast<const float2*>(ea + (size_t)e1 * D + c);
    const float2 x1 = *reinterpret_cast<const float2*>(x + (size_t)s1 * D + c);
    acc.x += fmaxf(x0.x + a0.x, 0.f);
    acc.y += fmaxf(x0.y + a0.y, 0.f);
    acc.x += fmaxf(x1.x + a1.x, 0.f);
    acc.y += fmaxf(x1.y + a1.y, 0.f);
  }
  if (j < jend) {
    int e0 = elist[j];
    int s0 = have_s ? slist[j] : ei[e0];
    const float2 a0 = *reinterpret_cast<const float2*>(ea + (size_t)e0 * D + c);
    const float2 x0 = *reinterpret_cast<const float2*>(x + (size_t)s0 * D + c);
    acc.x += fmaxf(x0.x + a0.x, 0.f);
    acc.y += fmaxf(x0.y + a0.y, 0.f);
  }
  *reinterpret_cast<float2*>(aggr + (size_t)node * D + c) = acc;
}

// ---------------------------------------------------------------------------
// Fused MLP: out = relu((1+eps)*x + aggr) @ W1 + b1) @ W2 + b2
// aggr may alias out (block reads only its own rows, writes at the end).
// ---------------------------------------------------------------------------
__global__ __launch_bounds__(256) void gine_mlp_kernel(
    const float* __restrict__ x, const float* aggr,
    const float* __restrict__ eps_p,
    const float* __restrict__ W1, const float* __restrict__ b1,
    const float* __restrict__ W2, const float* __restrict__ b2,
    float* out, int N) {
  __shared__ float zs[NPB][LDZ];
  const int tid = threadIdx.x;
  const int tx = tid & 31;
  const int ty = tid >> 5;
  const int n0 = blockIdx.x * NPB;
  const float epsp1 = 1.0f + eps_p[0];

  for (int i = tid; i < NPB * 32; i += 256) {
    int node = i >> 5;
    int c = (i & 31) << 2;
    int g = n0 + node;
    float4 zv = make_float4(0.f, 0.f, 0.f, 0.f);
    if (g < N) {
      float4 xv = *reinterpret_cast<const float4*>(x + (size_t)g * D + c);
      float4 av = *reinterpret_cast<const float4*>(aggr + (size_t)g * D + c);
      zv.x = epsp1 * xv.x + av.x;
      zv.y = epsp1 * xv.y + av.y;
      zv.z = epsp1 * xv.z + av.z;
      zv.w = epsp1 * xv.w + av.w;
    }
    zs[node][c + 0] = zv.x;
    zs[node][c + 1] = zv.y;
    zs[node][c + 2] = zv.z;
    zs[node][c + 3] = zv.w;
  }
  __syncthreads();

  float acc[8][4];

  // ---- Layer 1: h = relu(z @ W1 + b1) ----
  {
    const float4 bv = *reinterpret_cast<const float4*>(b1 + tx * 4);
#pragma unroll
    for (int r = 0; r < 8; ++r) {
      acc[r][0] = bv.x; acc[r][1] = bv.y; acc[r][2] = bv.z; acc[r][3] = bv.w;
    }
    for (int k = 0; k < D; k += 4) {
      float4 w0 = *reinterpret_cast<const float4*>(W1 + (size_t)(k + 0) * D + tx * 4);
      float4 w1 = *reinterpret_cast<const float4*>(W1 + (size_t)(k + 1) * D + tx * 4);
      float4 w2 = *reinterpret_cast<const float4*>(W1 + (size_t)(k + 2) * D + tx * 4);
      float4 w3 = *reinterpret_cast<const float4*>(W1 + (size_t)(k + 3) * D + tx * 4);
#pragma unroll
      for (int r = 0; r < 8; ++r) {
        float4 zv = *reinterpret_cast<const float4*>(&zs[ty * 8 + r][k]);
        acc[r][0] += zv.x * w0.x + zv.y * w1.x + zv.z * w2.x + zv.w * w3.x;
        acc[r][1] += zv.x * w0.y + zv.y * w1.y + zv.z * w2.y + zv.w * w3.y;
        acc[r][2] += zv.x * w0.z + zv.y * w1.z + zv.z * w2.z + zv.w * w3.z;
        acc[r][3] += zv.x * w0.w + zv.y * w1.w + zv.z * w2.w + zv.w * w3.w;
      }
    }
  }
  __syncthreads();

#pragma unroll
  for (int r = 0; r < 8; ++r) {
    float4 hv;
    hv.x = fmaxf(acc[r][0], 0.f);
    hv.y = fmaxf(acc[r][1], 0.f);
    hv.z = fmaxf(acc[r][2], 0.f);
    hv.w = fmaxf(acc[r][3], 0.f);
    *reinterpret_cast<float4*>(&zs[ty * 8 + r][tx * 4]) = hv;
  }
  __syncthreads();

  // ---- Layer 2: out = h @ W2 + b2 ----
  {
    const float4 bv = *reinterpret_cast<const float4*>(b2 + tx * 4);
#pragma unroll
    for (int r = 0; r < 8; ++r) {
      acc[r][0] = bv.x; acc[r][1] = bv.y; acc[r][2] = bv.z; acc[r][3] = bv.w;
    }
    for (int k = 0; k < D; k += 4) {
      float4 w0 = *reinterpret_cast<const float4*>(W2 + (size_t)(k + 0) * D + tx * 4);
      float4 w1 = *reinterpret_cast<const float4*>(W2 + (size_t)(k + 1) * D + tx * 4);
      float4 w2 = *reinterpret_cast<const float4*>(W2 + (size_t)(k + 2) * D + tx * 4);
      float4 w3 = *reinterpret_cast<const float4*>(W2 + (size_t)(k + 3) * D + tx * 4);
#pragma unroll
      for (int r = 0; r < 8; ++r) {
        float4 zv = *reinterpret_cast<const float4*>(&zs[ty * 8 + r][k]);
        acc[r][0] += zv.x * w0.x + zv.y * w1.x + zv.z * w2.x + zv.w * w3.x;
        acc[r][1] += zv.x * w0.y + zv.y * w1.y + zv.z * w2.y + zv.w * w3.y;
        acc[r][2] += zv.x * w0.z + zv.y * w1.z + zv.z * w2.z + zv.w * w3.z;
        acc[r][3] += zv.x * w0.w + zv.y * w1.w + zv.z * w2.w + zv.w * w3.w;
      }
    }
  }

#pragma unroll
  for (int r = 0; r < 8; ++r) {
    int g = n0 + ty * 8 + r;
    if (g < N) {
      float4 ov = make_float4(acc[r][0], acc[r][1], acc[r][2], acc[r][3]);
      *reinterpret_cast<float4*>(out + (size_t)g * D + tx * 4) = ov;
    }
  }
}

extern "C" void kernel_launch(void* const* d_in, const int* in_sizes, int n_in,
                              void* d_out, int out_size, void* d_ws, size_t ws_size,
                              hipStream_t stream) {
  const float* x   = (const float*)d_in[0];
  const int*   ei  = (const int*)d_in[1];
  const float* ea  = (const float*)d_in[2];
  const float* eps = (const float*)d_in[3];
  const float* W1  = (const float*)d_in[4];
  const float* b1  = (const float*)d_in[5];
  const float* W2  = (const float*)d_in[6];
  const float* b2  = (const float*)d_in[7];
  float* out = (float*)d_out;

  const int N = in_sizes[0] / D;
  const int E = in_sizes[1] / 2;

  const int eblocks = (E + 255) / 256;
  const size_t need1 = ((size_t)2 * N + 1 + (size_t)E) * sizeof(int);      // CSR
  const size_t need2 = ((size_t)2 * N + 1 + (size_t)2 * E) * sizeof(int);  // CSR+slist

  if (d_ws != nullptr && ws_size >= need1) {
    // ---- CSR gather path: no fp32 atomics ----
    int* cnt   = (int*)d_ws;        // [N]   degree counts, then fill cursor
    int* off   = cnt + N;           // [N+1] CSR offsets
    int* elist = off + N + 1;       // [E]   dst-bucketed edge ids
    int* slist = (ws_size >= need2) ? (elist + E) : nullptr;  // [E] src ids

    hipMemsetAsync(cnt, 0, (size_t)N * sizeof(int), stream);
    gine_hist_kernel<<<eblocks, 256, 0, stream>>>(ei, cnt, E);
    gine_scan_kernel<<<1, 1024, 0, stream>>>(cnt, off, N, E);
    gine_fill_kernel<<<eblocks, 256, 0, stream>>>(ei, cnt, elist, slist, E);

    const int ablocks = (N + 3) / 4;  // 4 waves/block, 1 wave per node
    gine_aggr_kernel<<<ablocks, 256, 0, stream>>>(x, ea, ei, off, elist, slist, out, N);
  } else {
    // ---- fallback: legacy atomic scatter ----
    hipMemsetAsync(d_out, 0, (size_t)out_size * sizeof(float), stream);
    long long tot = (long long)E * 32;
    int eb = (int)((tot + 255) / 256);
    gine_edge_atomic_kernel<<<eb, 256, 0, stream>>>(x, ei, ea, out, E);
  }

  const int nblocks = (N + NPB - 1) / NPB;
  gine_mlp_kernel<<<nblocks, 256, 0, stream>>>(x, out, eps, W1, b1, W2, b2, out, N);
}